// Round 1
// baseline (145.455 us; speedup 1.0000x reference)
//
#include <hip/hip_runtime.h>

#define BATCH 16
#define HH    256
#define OUTD  246      // HH - 2*w, w=5
#define TX    64       // output cols per block
#define TY    16       // output rows per block
#define LR    26       // TY + 10 input rows staged
#define PITCH 76       // staged floats per row (>= TX+12, mult of 4)
#define NPLANE 6       // 2 images x 3 channels

__device__ __forceinline__ float elem4(const float4& v, int k) {
  return k == 0 ? v.x : k == 1 ? v.y : k == 2 ? v.z : v.w;
}
__device__ __forceinline__ float sel8(const float4& a, const float4& b, int k) {
  return k < 4 ? elem4(a, k) : elem4(b, k - 4);
}

__global__ __launch_bounds__(256, 3)
void contrast_loss_kernel(const float* __restrict__ orig,
                          const float* __restrict__ sim,
                          float* __restrict__ out) {
  __shared__ float lds[NPLANE][LR][PITCH];
  __shared__ float wsum[4];

  const int tid = threadIdx.x;
  const int b   = blockIdx.z;
  const int tXo = blockIdx.x * TX;   // output-x base of tile (also input col base)
  const int tYo = blockIdx.y * TY;   // output-y base (input row base)

  const float* img0 = orig + (size_t)b * 3 * HH * HH;
  const float* img1 = sim  + (size_t)b * 3 * HH * HH;

  // ---------------- staging: global -> LDS (clamped at image edges) ----------------
  for (int t = tid; t < NPLANE * LR * 19; t += 256) {
    const int pl  = t / (LR * 19);
    const int rem = t - pl * (LR * 19);
    const int r   = rem / 19;
    const int c4  = rem - r * 19;
    const int im  = pl / 3;
    const int ch  = pl - im * 3;
    int row = tYo + r; row = row < HH ? row : HH - 1;   // clamped rows feed only masked lanes
    const float* src = (im ? img1 : img0) + ((size_t)ch * HH + row) * HH;
    const int col0 = tXo + 4 * c4;
    float4 v;
    if (col0 + 3 < HH) {
      v = *(const float4*)(src + col0);                 // 16B-aligned (tXo%64==0)
    } else {
      int c0 = col0 + 0; c0 = c0 < HH ? c0 : HH - 1;
      int c1 = col0 + 1; c1 = c1 < HH ? c1 : HH - 1;
      int c2 = col0 + 2; c2 = c2 < HH ? c2 : HH - 1;
      int c3 = col0 + 3; c3 = c3 < HH ? c3 : HH - 1;
      v.x = src[c0]; v.y = src[c1]; v.z = src[c2]; v.w = src[c3];
    }
    *(float4*)&lds[pl][r][4 * c4] = v;
  }
  __syncthreads();

  // ---------------- compute: each thread owns a 1x4 output strip ----------------
  const int tcol = tid & 15;
  const int trow = tid >> 4;
  const int x0 = tXo + 4 * tcol;   // first output x of strip
  const int y0 = tYo + trow;       // output y

  // center values: input (y0+5, x0+5+p)  -> lds row trow+5, col 4*tcol+5+p
  float cen[NPLANE][4];
  #pragma unroll
  for (int pl = 0; pl < NPLANE; ++pl) {
    #pragma unroll
    for (int p = 0; p < 4; ++p)
      cen[pl][p] = lds[pl][trow + 5][4 * tcol + 5 + p];
  }

  float acc[4] = {0.f, 0.f, 0.f, 0.f};

  // iterate all 121 shifts; (i=5,j=5) contributes exactly 0 so no skip needed.
  // shifted value for (p, i, j): input (y0+i, x0+p+j) -> lds[.. ][trow+i][4*tcol + p + j]
  #pragma unroll 1
  for (int i = 0; i < 11; ++i) {
    const int lr = trow + i;
    float4 wa[NPLANE], wb[NPLANE];
    #pragma unroll
    for (int pl = 0; pl < NPLANE; ++pl) {
      const float4* rp = (const float4*)&lds[pl][lr][4 * tcol];
      wa[pl] = rp[0];   // chunk0: reg idx 0..3
      wb[pl] = rp[1];   // chunk1: reg idx 4..7
    }

#define BODY(LOW, HIGH, IDX)                                                \
    {                                                                       \
      float so = fabsf(cen[0][p] - sel8(LOW[0], HIGH[0], (IDX)))            \
               + fabsf(cen[1][p] - sel8(LOW[1], HIGH[1], (IDX)))            \
               + fabsf(cen[2][p] - sel8(LOW[2], HIGH[2], (IDX)));           \
      float ss = fabsf(cen[3][p] - sel8(LOW[3], HIGH[3], (IDX)))            \
               + fabsf(cen[4][p] - sel8(LOW[4], HIGH[4], (IDX)))            \
               + fabsf(cen[5][p] - sel8(LOW[5], HIGH[5], (IDX)));           \
      acc[p] += fabsf(so - ss);                                             \
    }

    // j = 0..3 : idx = p+j in [0,6] over (chunk0, chunk1)
    #pragma unroll
    for (int j = 0; j < 4; ++j) {
      #pragma unroll
      for (int p = 0; p < 4; ++p) BODY(wa, wb, p + j)
    }

    #pragma unroll
    for (int pl = 0; pl < NPLANE; ++pl) {
      const float4* rp = (const float4*)&lds[pl][lr][4 * tcol];
      wa[pl] = rp[2];   // chunk2: reg idx 8..11
    }
    // j = 4..7 : idx = p+j-4 in [0,6] over (chunk1=wb, chunk2=wa)
    #pragma unroll
    for (int j = 4; j < 8; ++j) {
      #pragma unroll
      for (int p = 0; p < 4; ++p) BODY(wb, wa, p + j - 4)
    }

    #pragma unroll
    for (int pl = 0; pl < NPLANE; ++pl) {
      const float4* rp = (const float4*)&lds[pl][lr][4 * tcol];
      wb[pl] = rp[3];   // chunk3: reg idx 12..15
    }
    // j = 8..10 : idx = p+j-8 in [0,5] over (chunk2=wa, chunk3=wb)
    #pragma unroll
    for (int j = 8; j < 11; ++j) {
      #pragma unroll
      for (int p = 0; p < 4; ++p) BODY(wa, wb, p + j - 8)
    }
#undef BODY
  }

  // ---------------- mask invalid positions, reduce, atomic ----------------
  const bool vy = (y0 < OUTD);
  float s = 0.f;
  #pragma unroll
  for (int p = 0; p < 4; ++p)
    s += (vy && (x0 + p) < OUTD) ? acc[p] : 0.f;

  #pragma unroll
  for (int off = 32; off > 0; off >>= 1)
    s += __shfl_down(s, off, 64);

  const int wave = tid >> 6;
  if ((tid & 63) == 0) wsum[wave] = s;
  __syncthreads();
  if (tid == 0) {
    const float scale = 1.0f / 116190720.0f;  // 16*246*246*120
    atomicAdd(out, (wsum[0] + wsum[1] + wsum[2] + wsum[3]) * scale);
  }
}

extern "C" void kernel_launch(void* const* d_in, const int* in_sizes, int n_in,
                              void* d_out, int out_size, void* d_ws, size_t ws_size,
                              hipStream_t stream) {
  (void)in_sizes; (void)n_in; (void)d_ws; (void)ws_size; (void)out_size;
  const float* orig = (const float*)d_in[0];
  const float* sim  = (const float*)d_in[1];
  float* out = (float*)d_out;

  hipMemsetAsync(out, 0, sizeof(float), stream);  // graph-capturable memset node

  dim3 grid((OUTD + TX - 1) / TX, (OUTD + TY - 1) / TY, BATCH);  // 4 x 16 x 16
  dim3 block(256);
  hipLaunchKernelGGL(contrast_loss_kernel, grid, block, 0, stream, orig, sim, out);
}

// Round 2
// 116.628 us; speedup vs baseline: 1.2472x; 1.2472x over previous
//
#include <hip/hip_runtime.h>

#define BATCH 16
#define HH    256
#define OUTD  246          // 256 - 2*5
#define PITCH 80           // LDS row pitch in floats; 80 % 32 == 16 -> 2-way max
#define ROWS  21           // 16 tile rows + 5 halo
#define PLSTRIDE (ROWS * PITCH)      // 1680 floats per plane
#define SMFLOATS (6 * PLSTRIDE)      // 10080 floats = 40320 B

__device__ __forceinline__ float elem4(const float4 v, int k) {
  return k == 0 ? v.x : k == 1 ? v.y : k == 2 ? v.z : v.w;
}

// Window element IDX in [0,13]: 0..11 from W[pl][0..2], 12..13 from E[pl].
#define EL(PL, IDX)                                                         \
  ((IDX) < 12 ? elem4(W[(PL)][(((IDX) < 12 ? (IDX) : 0) >> 2)], (IDX)&3)    \
              : ((IDX) == 12 ? E[(PL)].x : E[(PL)].y))

#define DIFF6(P, IDX, FV)                                                   \
  float FV;                                                                 \
  {                                                                         \
    float so_ = fabsf(cen[0][(P)] - EL(0, IDX))                             \
              + fabsf(cen[1][(P)] - EL(1, IDX))                             \
              + fabsf(cen[2][(P)] - EL(2, IDX));                            \
    float ss_ = fabsf(cen[3][(P)] - EL(3, IDX))                             \
              + fabsf(cen[4][(P)] - EL(4, IDX))                             \
              + fabsf(cen[5][(P)] - EL(5, IDX));                            \
    FV = fabsf(so_ - ss_);                                                  \
  }

// fast: weight 2 applied at the end
#define SF(P, J) { DIFF6(P, (P) + (J) + 5, f_) accV[(P)] += f_; }
// masked: accV masked by m0 at end; accS masked per-shift by m1
#define SMK(P, J)                                                           \
  { DIFF6(P, (P) + (J) + 5, f_) accV[(P)] += f_;                            \
    accS[(P)] += (yok && ((unsigned)(xp[(P)] + (J)) < 246u)) ? f_ : 0.0f; }

#define JF(J) SF(0, J) SF(1, J) SF(2, J) SF(3, J)
#define JM(J) SMK(0, J) SMK(1, J) SMK(2, J) SMK(3, J)

#define LOADW(BP)                                                           \
  { const float* bp_ = (BP);                                                \
    _Pragma("unroll") for (int pl_ = 0; pl_ < 6; ++pl_) {                   \
      W[pl_][0] = *(const float4*)(bp_ + pl_ * PLSTRIDE);                   \
      W[pl_][1] = *(const float4*)(bp_ + pl_ * PLSTRIDE + 4);               \
      W[pl_][2] = *(const float4*)(bp_ + pl_ * PLSTRIDE + 8);               \
      E[pl_]    = *(const float2*)(bp_ + pl_ * PLSTRIDE + 12);              \
    } }

__global__ __launch_bounds__(256, 3)
void contrast_loss_kernel(const float* __restrict__ orig,
                          const float* __restrict__ sim,
                          float* __restrict__ out) {
  __shared__ float sm[SMFLOATS];
  __shared__ float wsum[4];

  const int tid = threadIdx.x;
  const int bx = blockIdx.x, by = blockIdx.y, b = blockIdx.z;
  const int cbase = bx * 64 - 5;  // image col of LDS col 0 (also p'x of col 0)
  const int rbase = by * 16;      // image row of LDS row 0

  const float* img0 = orig + (size_t)b * 3 * HH * HH;
  const float* img1 = sim  + (size_t)b * 3 * HH * HH;

  // ---- staging: 6 planes x 21 rows x 80 cols, scalar, clamped ----
  for (int t = tid; t < SMFLOATS; t += 256) {
    const int pl  = t / PLSTRIDE;
    const int rem = t - pl * PLSTRIDE;
    const int r   = rem / PITCH;
    const int c   = rem - r * PITCH;
    const int im  = pl / 3;
    const int ch  = pl - im * 3;
    int row = rbase + r; row = row < HH ? row : HH - 1;
    int col = cbase + c; col = col < 0 ? 0 : (col < HH ? col : HH - 1);
    const float* src = (im ? img1 : img0) + ((size_t)ch * HH + row) * HH;
    sm[t] = src[col];
  }
  __syncthreads();

  // ---- thread geometry: wave footprint = 32 cols x 8 rows ----
  const int lane  = tid & 63;
  const int wave  = tid >> 6;
  const int xhalf = wave & 1;
  const int ywave = wave >> 1;
  const int xi = xhalf * 32 + (lane & 7) * 4;   // LDS col of window start
  const int yi = ywave * 8 + (lane >> 3);       // LDS row of center row

  const int y   = rbase + yi - 5;   // p'_y
  const int xp0 = cbase + xi;       // p'_x for p=0

  float4 W[6][3];
  float2 E[6];
  float  cen[6][4];
  float  accV[4] = {0.f, 0.f, 0.f, 0.f};
  float  accS[4] = {0.f, 0.f, 0.f, 0.f};

  const float* base = &sm[yi * PITCH + xi];

  // wave-uniform interior test: all lanes have m0=1 and m1=1 for all 60 shifts
  const int wx_lo = cbase + xhalf * 32;
  const int wy_lo = rbase - 5 + ywave * 8;
  const bool fastw = (wx_lo >= 5) && (wx_lo + 31 <= 240) &&
                     (wy_lo >= 0) && (wy_lo + 7 <= 240);

  // i = 0 window (center row)
  LOADW(base);
  #pragma unroll
  for (int pl = 0; pl < 6; ++pl) {     // center = window idx p+5
    cen[pl][0] = W[pl][1].y;
    cen[pl][1] = W[pl][1].z;
    cen[pl][2] = W[pl][1].w;
    cen[pl][3] = W[pl][2].x;
  }

  float tot;
  if (fastw) {
    // i = 0: j = 1..5
    JF(1) JF(2) JF(3) JF(4) JF(5)
    #pragma unroll 1
    for (int ii = 1; ii <= 5; ++ii) {
      base += PITCH;
      LOADW(base);
      JF(-5) JF(-4) JF(-3) JF(-2) JF(-1) JF(0) JF(1) JF(2) JF(3) JF(4) JF(5)
    }
    tot = 2.0f * (accV[0] + accV[1] + accV[2] + accV[3]);
  } else {
    const int xp[4] = {xp0, xp0 + 1, xp0 + 2, xp0 + 3};
    bool yok = ((unsigned)y < 246u);            // i = 0
    JM(1) JM(2) JM(3) JM(4) JM(5)
    #pragma unroll 1
    for (int ii = 1; ii <= 5; ++ii) {
      base += PITCH;
      LOADW(base);
      yok = ((unsigned)(y + ii) < 246u);
      JM(-5) JM(-4) JM(-3) JM(-2) JM(-1) JM(0) JM(1) JM(2) JM(3) JM(4) JM(5)
    }
    tot = 0.f;
    const bool ym0 = ((unsigned)y < 246u);
    #pragma unroll
    for (int p = 0; p < 4; ++p) {
      const bool m0 = ym0 && ((unsigned)xp[p] < 246u);
      tot += (m0 ? accV[p] : 0.f) + accS[p];
    }
  }

  // ---- reduce: wave shuffle -> LDS -> one atomic per block ----
  #pragma unroll
  for (int off = 32; off > 0; off >>= 1)
    tot += __shfl_down(tot, off, 64);
  if (lane == 0) wsum[wave] = tot;
  __syncthreads();
  if (tid == 0) {
    const float scale = 1.0f / 116190720.0f;   // 16*246*246*120
    atomicAdd(out, (wsum[0] + wsum[1] + wsum[2] + wsum[3]) * scale);
  }
}

extern "C" void kernel_launch(void* const* d_in, const int* in_sizes, int n_in,
                              void* d_out, int out_size, void* d_ws, size_t ws_size,
                              hipStream_t stream) {
  (void)in_sizes; (void)n_in; (void)d_ws; (void)ws_size; (void)out_size;
  const float* orig = (const float*)d_in[0];
  const float* sim  = (const float*)d_in[1];
  float* out = (float*)d_out;

  hipMemsetAsync(out, 0, sizeof(float), stream);

  dim3 grid(4, 16, BATCH);   // x: 4x64 cols of extended domain, y: 16x16 rows
  dim3 block(256);
  hipLaunchKernelGGL(contrast_loss_kernel, grid, block, 0, stream, orig, sim, out);
}